// Round 3
// baseline (870.305 us; speedup 1.0000x reference)
//
#include <hip/hip_runtime.h>

// GCN forward: 2× (GCNConv) + mean-pool + linear head, all f32.
// Pipeline per call (ws is re-poisoned every call, so CSR is rebuilt each time):
//   count in-deg -> dinv -> exclusive scan -> scatter (CSR by dst)
//   t = (x@W1)*dinv ; h1 = relu((sum_in t + t[self])*dinv + b1)
//   t = (h1@W2)*dinv ; per-node scalar = ((sum_in t + t[self])*dinv + b2)·Wl
//   graph mean of scalars + bl -> out[512]
//
// R2: edge loop unrolled x8 -> 335->245 us per agg (latency-bound).
// R3: edge loop unrolled x16 (8 accumulators, 16 gathers in flight) to test
//     whether the wall is per-wave in-flight queue depth vs per-CU MSHR cap.

__global__ void k_count(const int* __restrict__ dst, int* __restrict__ cnt, int E) {
    int e = blockIdx.x * blockDim.x + threadIdx.x;
    if (e < E) atomicAdd(&cnt[dst[e]], 1);
}

__global__ void k_dinv(const int* __restrict__ cnt, float* __restrict__ dinv, int N) {
    int i = blockIdx.x * blockDim.x + threadIdx.x;
    if (i < N) dinv[i] = 1.0f / sqrtf((float)cnt[i] + 1.0f);  // +1 self loop
}

// Exclusive scan of cnt[N] -> rp[N]; per-chunk totals to bsum.
__global__ void k_scan_a(const int* __restrict__ cnt, int* __restrict__ rp,
                         int* __restrict__ bsum, int N) {
    __shared__ int tmp[1024];
    int i = blockIdx.x * 1024 + threadIdx.x;
    int v = (i < N) ? cnt[i] : 0;
    tmp[threadIdx.x] = v;
    __syncthreads();
    for (int off = 1; off < 1024; off <<= 1) {
        int t = (threadIdx.x >= off) ? tmp[threadIdx.x - off] : 0;
        __syncthreads();
        tmp[threadIdx.x] += t;
        __syncthreads();
    }
    if (i < N) rp[i] = (threadIdx.x == 0) ? 0 : tmp[threadIdx.x - 1];
    if (threadIdx.x == 1023) bsum[blockIdx.x] = tmp[1023];
}

// Exclusive scan of chunk totals (nb <= 128).
__global__ void k_scan_b(int* __restrict__ bsum, int nb) {
    __shared__ int tmp[128];
    int t = threadIdx.x;
    int v = (t < nb) ? bsum[t] : 0;
    tmp[t] = v;
    __syncthreads();
    for (int off = 1; off < 128; off <<= 1) {
        int u = (t >= off) ? tmp[t - off] : 0;
        __syncthreads();
        tmp[t] += u;
        __syncthreads();
    }
    if (t < nb) bsum[t] = (t == 0) ? 0 : tmp[t - 1];
}

__global__ void k_scan_c(int* __restrict__ rp, const int* __restrict__ bsum,
                         int* __restrict__ cur, int N, int E) {
    int i = blockIdx.x * blockDim.x + threadIdx.x;
    if (i < N) {
        int v = rp[i] + bsum[i >> 10];
        rp[i] = v;
        cur[i] = v;
    } else if (i == N) {
        rp[N] = E;
    }
}

__global__ void k_scatter(const int* __restrict__ src, const int* __restrict__ dst,
                          int* __restrict__ cur, int* __restrict__ srt, int E) {
    int e = blockIdx.x * blockDim.x + threadIdx.x;
    if (e < E) {
        int d = dst[e];
        int pos = atomicAdd(&cur[d], 1);
        srt[pos] = src[e];
    }
}

// C[r][:] = (A[r][:] @ B) * dinv[r];  A: N x 128, B: 128 x 128 row-major.
// Classic 128x128 block, 8x8 per thread, BK=8.
__global__ __launch_bounds__(256) void k_mm_scale(
    const float* __restrict__ A, const float* __restrict__ B,
    const float* __restrict__ dinv, float* __restrict__ C, int N)
{
    __shared__ float As[8][128];   // [k][m] (transposed store)
    __shared__ float Bs[8][128];   // [k][n]
    int tid = threadIdx.x;
    int row0 = blockIdx.x * 128;
    int a_row = tid >> 1;            // 0..127
    int a_col = (tid & 1) * 4;       // 0 or 4
    int b_row = tid >> 5;            // 0..7
    int b_col = (tid & 31) * 4;      // 0..124
    int tx = tid & 15;               // col group (8 cols each)
    int ty = tid >> 4;               // row group (8 rows each)

    float acc[8][8];
#pragma unroll
    for (int i = 0; i < 8; ++i)
#pragma unroll
        for (int j = 0; j < 8; ++j) acc[i][j] = 0.0f;

    for (int k0 = 0; k0 < 128; k0 += 8) {
        int gr = row0 + a_row;
        if (gr > N - 1) gr = N - 1;   // clamp: OOB rows discarded at store
        float4 av = *(const float4*)(A + (size_t)gr * 128 + k0 + a_col);
        float4 bv = *(const float4*)(B + (size_t)(k0 + b_row) * 128 + b_col);
        As[a_col + 0][a_row] = av.x;
        As[a_col + 1][a_row] = av.y;
        As[a_col + 2][a_row] = av.z;
        As[a_col + 3][a_row] = av.w;
        *(float4*)&Bs[b_row][b_col] = bv;
        __syncthreads();
#pragma unroll
        for (int kk = 0; kk < 8; ++kk) {
            float a[8], b[8];
#pragma unroll
            for (int i = 0; i < 8; ++i) a[i] = As[kk][ty * 8 + i];
#pragma unroll
            for (int j = 0; j < 8; ++j) b[j] = Bs[kk][tx * 8 + j];
#pragma unroll
            for (int i = 0; i < 8; ++i)
#pragma unroll
                for (int j = 0; j < 8; ++j)
                    acc[i][j] = fmaf(a[i], b[j], acc[i][j]);
        }
        __syncthreads();
    }

#pragma unroll
    for (int i = 0; i < 8; ++i) {
        int r = row0 + ty * 8 + i;
        if (r < N) {
            float s = dinv[r];
            float4 o0 = {acc[i][0] * s, acc[i][1] * s, acc[i][2] * s, acc[i][3] * s};
            float4 o1 = {acc[i][4] * s, acc[i][5] * s, acc[i][6] * s, acc[i][7] * s};
            *(float4*)(C + (size_t)r * 128 + tx * 8) = o0;
            *(float4*)(C + (size_t)r * 128 + tx * 8 + 4) = o1;
        }
    }
}

// Edge accumulation with up to 16 gathers in flight: returns sum over
// in-edges (pre-scaled rows) + self row, as a float2 per lane.
__device__ __forceinline__ float2 edge_accum(
    const float* __restrict__ t, const int* __restrict__ srt,
    int s0, int s1, int node, int lane)
{
    int fo = lane * 2;
    // Self row issued first so it overlaps the loop.
    float2 vs = *(const float2*)(t + (size_t)node * 128 + fo);

    float2 a[8];
#pragma unroll
    for (int j = 0; j < 8; ++j) a[j] = make_float2(0.0f, 0.0f);

    int e = s0;
    while (e + 16 <= s1) {
        int idx[16];
#pragma unroll
        for (int j = 0; j < 16; ++j) idx[j] = srt[e + j];   // wave-uniform, contiguous
        float2 v[16];
#pragma unroll
        for (int j = 0; j < 16; ++j)
            v[j] = *(const float2*)(t + (size_t)idx[j] * 128 + fo);
#pragma unroll
        for (int j = 0; j < 16; ++j) {
            a[j & 7].x += v[j].x;
            a[j & 7].y += v[j].y;
        }
        e += 16;
    }
    if (e + 8 <= s1) {
        int idx[8];
#pragma unroll
        for (int j = 0; j < 8; ++j) idx[j] = srt[e + j];
        float2 v[8];
#pragma unroll
        for (int j = 0; j < 8; ++j)
            v[j] = *(const float2*)(t + (size_t)idx[j] * 128 + fo);
#pragma unroll
        for (int j = 0; j < 8; ++j) {
            a[j].x += v[j].x;
            a[j].y += v[j].y;
        }
        e += 8;
    }
    if (e + 4 <= s1) {
        int idx[4];
#pragma unroll
        for (int j = 0; j < 4; ++j) idx[j] = srt[e + j];
        float2 v[4];
#pragma unroll
        for (int j = 0; j < 4; ++j)
            v[j] = *(const float2*)(t + (size_t)idx[j] * 128 + fo);
#pragma unroll
        for (int j = 0; j < 4; ++j) {
            a[j].x += v[j].x;
            a[j].y += v[j].y;
        }
        e += 4;
    }
    for (; e < s1; ++e) {
        int s = srt[e];
        float2 v = *(const float2*)(t + (size_t)s * 128 + fo);
        a[0].x += v.x;
        a[0].y += v.y;
    }
    float2 acc;
    acc.x = ((a[0].x + a[1].x) + (a[2].x + a[3].x)) +
            ((a[4].x + a[5].x) + (a[6].x + a[7].x)) + vs.x;
    acc.y = ((a[0].y + a[1].y) + (a[2].y + a[3].y)) +
            ((a[4].y + a[5].y) + (a[6].y + a[7].y)) + vs.y;
    return acc;
}

// One wave (64 lanes, float2/lane) per node: sum pre-scaled rows of in-edges.
__global__ __launch_bounds__(256) void k_agg1(
    const float* __restrict__ t, const float* __restrict__ dinv,
    const int* __restrict__ rp, const int* __restrict__ srt,
    const float* __restrict__ b1, float* __restrict__ hout, int N)
{
    int wave = threadIdx.x >> 6;
    int lane = threadIdx.x & 63;
    int node = blockIdx.x * 4 + wave;
    if (node >= N) return;
    int s0 = rp[node], s1 = rp[node + 1];
    float2 acc = edge_accum(t, srt, s0, s1, node, lane);
    float di = dinv[node];
    float2 bb = *(const float2*)(b1 + lane * 2);
    float2 o;
    o.x = fmaxf(fmaf(acc.x, di, bb.x), 0.0f);
    o.y = fmaxf(fmaf(acc.y, di, bb.y), 0.0f);
    *(float2*)(hout + (size_t)node * 128 + lane * 2) = o;
}

// Layer-2 aggregation fused with the linear head: per-node scalar h2·Wl,
// shuffle-reduced across the wave, one atomicAdd per node into graph sums.
__global__ __launch_bounds__(256) void k_agg2(
    const float* __restrict__ t, const float* __restrict__ dinv,
    const int* __restrict__ rp, const int* __restrict__ srt,
    const float* __restrict__ b2, const float* __restrict__ Wl,
    const int* __restrict__ batch, float* __restrict__ gsum,
    int* __restrict__ gcnt, int N)
{
    int wave = threadIdx.x >> 6;
    int lane = threadIdx.x & 63;
    int node = blockIdx.x * 4 + wave;
    if (node >= N) return;
    int s0 = rp[node], s1 = rp[node + 1];
    float2 acc = edge_accum(t, srt, s0, s1, node, lane);
    float di = dinv[node];
    float2 bb = *(const float2*)(b2 + lane * 2);
    float2 wl = *(const float2*)(Wl + lane * 2);
    float hx = fmaf(acc.x, di, bb.x);
    float hy = fmaf(acc.y, di, bb.y);
    float p = hx * wl.x + hy * wl.y;
#pragma unroll
    for (int off = 32; off > 0; off >>= 1) p += __shfl_down(p, off);
    if (lane == 0) {
        int g = batch[node];
        atomicAdd(&gsum[g], p);
        atomicAdd(&gcnt[g], 1);
    }
}

__global__ void k_final(const float* __restrict__ gsum, const int* __restrict__ gcnt,
                        const float* __restrict__ bl, float* __restrict__ out, int G) {
    int g = blockIdx.x * blockDim.x + threadIdx.x;
    if (g < G) out[g] = gsum[g] / fmaxf((float)gcnt[g], 1.0f) + bl[0];
}

extern "C" void kernel_launch(void* const* d_in, const int* in_sizes, int n_in,
                              void* d_out, int out_size, void* d_ws, size_t ws_size,
                              hipStream_t stream)
{
    const float* x  = (const float*)d_in[0];
    const int*   ei = (const int*)d_in[1];
    // d_in[2] = edge_attr: unused by the reference
    const int*   batch = (const int*)d_in[3];
    const float* W1 = (const float*)d_in[4];
    const float* b1 = (const float*)d_in[5];
    const float* W2 = (const float*)d_in[6];
    const float* b2 = (const float*)d_in[7];
    const float* Wl = (const float*)d_in[8];
    const float* bl = (const float*)d_in[9];

    int N = in_sizes[0] / 128;
    int E = in_sizes[1] / 2;
    const int* src = ei;
    const int* dst = ei + E;

    char* ws = (char*)d_ws;
    size_t off = 0;
    auto alloc = [&](size_t bytes) -> void* {
        void* p = ws + off;
        off = (off + bytes + 255) & ~(size_t)255;
        return p;
    };
    float* t    = (float*)alloc((size_t)N * 128 * 4);
    float* h1   = (float*)alloc((size_t)N * 128 * 4);
    int*   srt  = (int*)alloc((size_t)E * 4);
    int*   cnt  = (int*)alloc((size_t)N * 4);
    float* dinv = (float*)alloc((size_t)N * 4);
    int*   rp   = (int*)alloc((size_t)(N + 1) * 4);
    int*   cur  = (int*)alloc((size_t)N * 4);
    int*   bsum = (int*)alloc(1024 * 4);
    float* gsum = (float*)alloc(512 * 4);
    int*   gcnt = (int*)alloc(512 * 4);
    (void)ws_size;

    hipMemsetAsync(cnt, 0, (size_t)N * 4, stream);
    hipMemsetAsync(gsum, 0, 512 * 4, stream);
    hipMemsetAsync(gcnt, 0, 512 * 4, stream);

    int eb = (E + 255) / 256;
    int nb = (N + 255) / 256;
    k_count<<<eb, 256, 0, stream>>>(dst, cnt, E);
    k_dinv<<<nb, 256, 0, stream>>>(cnt, dinv, N);
    int nchunk = (N + 1023) / 1024;   // 98 <= 128 (k_scan_b capacity)
    k_scan_a<<<nchunk, 1024, 0, stream>>>(cnt, rp, bsum, N);
    k_scan_b<<<1, 128, 0, stream>>>(bsum, nchunk);
    k_scan_c<<<(N + 256) / 256, 256, 0, stream>>>(rp, bsum, cur, N, E);
    k_scatter<<<eb, 256, 0, stream>>>(src, dst, cur, srt, E);

    int mmb = (N + 127) / 128;
    k_mm_scale<<<mmb, 256, 0, stream>>>(x, W1, dinv, t, N);
    k_agg1<<<(N + 3) / 4, 256, 0, stream>>>(t, dinv, rp, srt, b1, h1, N);
    k_mm_scale<<<mmb, 256, 0, stream>>>(h1, W2, dinv, t, N);
    k_agg2<<<(N + 3) / 4, 256, 0, stream>>>(t, dinv, rp, srt, b2, Wl, batch, gsum, gcnt, N);
    k_final<<<2, 256, 0, stream>>>(gsum, gcnt, bl, (float*)d_out, 512);
}

// Round 4
// 784.540 us; speedup vs baseline: 1.1093x; 1.1093x over previous
//
#include <hip/hip_runtime.h>

// GCN forward: 2× (GCNConv) + mean-pool + linear head.
// Pipeline per call (ws is re-poisoned every call, so CSR is rebuilt each time):
//   count in-deg -> dinv -> exclusive scan -> scatter (CSR by dst)
//   t = bf16((x@W1)*dinv) ; h1 = relu((sum_in t + t[self])*dinv + b1)   [h1 f32]
//   t = bf16((h1@W2)*dinv); per-node scalar = ((sum_in t + t[self])*dinv + b2)·Wl
//   graph mean of scalars + bl -> out[512]
//
// R2: edge loop unrolled x8 -> 335->245 us per agg (latency-bound).
// R3: unroll x16 REGRESSED (occupancy 65->43%); reverted to x8.
// R4: t tables stored bf16 (row 512B->256B = 4->2 cache lines/gather).
//     Aggs are bound by per-CU lines-in-flight x latency, so halving the
//     lines per row should ~halve agg time. Accumulation stays f32.

__device__ __forceinline__ unsigned bf16pair(float a, float b) {
    unsigned ua = __float_as_uint(a);
    unsigned ub = __float_as_uint(b);
    unsigned ra = (ua + 0x7FFFu + ((ua >> 16) & 1u)) >> 16;
    unsigned rb = (ub + 0x7FFFu + ((ub >> 16) & 1u)) & 0xFFFF0000u;
    return ra | rb;
}

__global__ void k_count(const int* __restrict__ dst, int* __restrict__ cnt, int E) {
    int e = blockIdx.x * blockDim.x + threadIdx.x;
    if (e < E) atomicAdd(&cnt[dst[e]], 1);
}

__global__ void k_dinv(const int* __restrict__ cnt, float* __restrict__ dinv, int N) {
    int i = blockIdx.x * blockDim.x + threadIdx.x;
    if (i < N) dinv[i] = 1.0f / sqrtf((float)cnt[i] + 1.0f);  // +1 self loop
}

// Exclusive scan of cnt[N] -> rp[N]; per-chunk totals to bsum.
__global__ void k_scan_a(const int* __restrict__ cnt, int* __restrict__ rp,
                         int* __restrict__ bsum, int N) {
    __shared__ int tmp[1024];
    int i = blockIdx.x * 1024 + threadIdx.x;
    int v = (i < N) ? cnt[i] : 0;
    tmp[threadIdx.x] = v;
    __syncthreads();
    for (int off = 1; off < 1024; off <<= 1) {
        int t = (threadIdx.x >= off) ? tmp[threadIdx.x - off] : 0;
        __syncthreads();
        tmp[threadIdx.x] += t;
        __syncthreads();
    }
    if (i < N) rp[i] = (threadIdx.x == 0) ? 0 : tmp[threadIdx.x - 1];
    if (threadIdx.x == 1023) bsum[blockIdx.x] = tmp[1023];
}

// Exclusive scan of chunk totals (nb <= 128).
__global__ void k_scan_b(int* __restrict__ bsum, int nb) {
    __shared__ int tmp[128];
    int t = threadIdx.x;
    int v = (t < nb) ? bsum[t] : 0;
    tmp[t] = v;
    __syncthreads();
    for (int off = 1; off < 128; off <<= 1) {
        int u = (t >= off) ? tmp[t - off] : 0;
        __syncthreads();
        tmp[t] += u;
        __syncthreads();
    }
    if (t < nb) bsum[t] = (t == 0) ? 0 : tmp[t - 1];
}

__global__ void k_scan_c(int* __restrict__ rp, const int* __restrict__ bsum,
                         int* __restrict__ cur, int N, int E) {
    int i = blockIdx.x * blockDim.x + threadIdx.x;
    if (i < N) {
        int v = rp[i] + bsum[i >> 10];
        rp[i] = v;
        cur[i] = v;
    } else if (i == N) {
        rp[N] = E;
    }
}

__global__ void k_scatter(const int* __restrict__ src, const int* __restrict__ dst,
                          int* __restrict__ cur, int* __restrict__ srt, int E) {
    int e = blockIdx.x * blockDim.x + threadIdx.x;
    if (e < E) {
        int d = dst[e];
        int pos = atomicAdd(&cur[d], 1);
        srt[pos] = src[e];
    }
}

// Cb[r][:] = bf16( (A[r][:] @ B) * dinv[r] );  A: N x 128 f32, B: 128 x 128 f32.
// Cb rows are 64 uints (2 bf16 each). Classic 128x128 block, 8x8/thread, BK=8.
__global__ __launch_bounds__(256) void k_mm_scale(
    const float* __restrict__ A, const float* __restrict__ B,
    const float* __restrict__ dinv, unsigned* __restrict__ Cb, int N)
{
    __shared__ float As[8][128];   // [k][m] (transposed store)
    __shared__ float Bs[8][128];   // [k][n]
    int tid = threadIdx.x;
    int row0 = blockIdx.x * 128;
    int a_row = tid >> 1;            // 0..127
    int a_col = (tid & 1) * 4;       // 0 or 4
    int b_row = tid >> 5;            // 0..7
    int b_col = (tid & 31) * 4;      // 0..124
    int tx = tid & 15;               // col group (8 cols each)
    int ty = tid >> 4;               // row group (8 rows each)

    float acc[8][8];
#pragma unroll
    for (int i = 0; i < 8; ++i)
#pragma unroll
        for (int j = 0; j < 8; ++j) acc[i][j] = 0.0f;

    for (int k0 = 0; k0 < 128; k0 += 8) {
        int gr = row0 + a_row;
        if (gr > N - 1) gr = N - 1;   // clamp: OOB rows discarded at store
        float4 av = *(const float4*)(A + (size_t)gr * 128 + k0 + a_col);
        float4 bv = *(const float4*)(B + (size_t)(k0 + b_row) * 128 + b_col);
        As[a_col + 0][a_row] = av.x;
        As[a_col + 1][a_row] = av.y;
        As[a_col + 2][a_row] = av.z;
        As[a_col + 3][a_row] = av.w;
        *(float4*)&Bs[b_row][b_col] = bv;
        __syncthreads();
#pragma unroll
        for (int kk = 0; kk < 8; ++kk) {
            float a[8], b[8];
#pragma unroll
            for (int i = 0; i < 8; ++i) a[i] = As[kk][ty * 8 + i];
#pragma unroll
            for (int j = 0; j < 8; ++j) b[j] = Bs[kk][tx * 8 + j];
#pragma unroll
            for (int i = 0; i < 8; ++i)
#pragma unroll
                for (int j = 0; j < 8; ++j)
                    acc[i][j] = fmaf(a[i], b[j], acc[i][j]);
        }
        __syncthreads();
    }

#pragma unroll
    for (int i = 0; i < 8; ++i) {
        int r = row0 + ty * 8 + i;
        if (r < N) {
            float s = dinv[r];
            uint4 o;
            o.x = bf16pair(acc[i][0] * s, acc[i][1] * s);
            o.y = bf16pair(acc[i][2] * s, acc[i][3] * s);
            o.z = bf16pair(acc[i][4] * s, acc[i][5] * s);
            o.w = bf16pair(acc[i][6] * s, acc[i][7] * s);
            *(uint4*)(Cb + (size_t)r * 64 + tx * 4) = o;
        }
    }
}

// Edge accumulation over bf16 rows, 8 gathers in flight; returns f32 sum over
// in-edges + self row. Lane holds features {2*lane, 2*lane+1} in (x,y).
__device__ __forceinline__ float2 edge_accum(
    const unsigned* __restrict__ t, const int* __restrict__ srt,
    int s0, int s1, int node, int lane)
{
    float2 a0 = {0,0}, a1 = {0,0}, a2 = {0,0}, a3 = {0,0};
    int e = s0;
    while (e + 8 <= s1) {
        int idx[8];
#pragma unroll
        for (int j = 0; j < 8; ++j) idx[j] = srt[e + j];
        unsigned w[8];
#pragma unroll
        for (int j = 0; j < 8; ++j)
            w[j] = t[(size_t)idx[j] * 64 + lane];
        a0.x += __uint_as_float(w[0] << 16);         a0.y += __uint_as_float(w[0] & 0xFFFF0000u);
        a1.x += __uint_as_float(w[1] << 16);         a1.y += __uint_as_float(w[1] & 0xFFFF0000u);
        a2.x += __uint_as_float(w[2] << 16);         a2.y += __uint_as_float(w[2] & 0xFFFF0000u);
        a3.x += __uint_as_float(w[3] << 16);         a3.y += __uint_as_float(w[3] & 0xFFFF0000u);
        a0.x += __uint_as_float(w[4] << 16);         a0.y += __uint_as_float(w[4] & 0xFFFF0000u);
        a1.x += __uint_as_float(w[5] << 16);         a1.y += __uint_as_float(w[5] & 0xFFFF0000u);
        a2.x += __uint_as_float(w[6] << 16);         a2.y += __uint_as_float(w[6] & 0xFFFF0000u);
        a3.x += __uint_as_float(w[7] << 16);         a3.y += __uint_as_float(w[7] & 0xFFFF0000u);
        e += 8;
    }
    if (e + 4 <= s1) {
        int idx[4];
#pragma unroll
        for (int j = 0; j < 4; ++j) idx[j] = srt[e + j];
        unsigned w[4];
#pragma unroll
        for (int j = 0; j < 4; ++j)
            w[j] = t[(size_t)idx[j] * 64 + lane];
        a0.x += __uint_as_float(w[0] << 16);         a0.y += __uint_as_float(w[0] & 0xFFFF0000u);
        a1.x += __uint_as_float(w[1] << 16);         a1.y += __uint_as_float(w[1] & 0xFFFF0000u);
        a2.x += __uint_as_float(w[2] << 16);         a2.y += __uint_as_float(w[2] & 0xFFFF0000u);
        a3.x += __uint_as_float(w[3] << 16);         a3.y += __uint_as_float(w[3] & 0xFFFF0000u);
        e += 4;
    }
    for (; e < s1; ++e) {
        unsigned w = t[(size_t)srt[e] * 64 + lane];
        a0.x += __uint_as_float(w << 16);
        a0.y += __uint_as_float(w & 0xFFFF0000u);
    }
    unsigned ws = t[(size_t)node * 64 + lane];   // self loop
    float2 acc;
    acc.x = (a0.x + a1.x) + (a2.x + a3.x) + __uint_as_float(ws << 16);
    acc.y = (a0.y + a1.y) + (a2.y + a3.y) + __uint_as_float(ws & 0xFFFF0000u);
    return acc;
}

// One wave per node: sum pre-scaled bf16 rows of in-edges; h1 out in f32.
__global__ __launch_bounds__(256) void k_agg1(
    const unsigned* __restrict__ t, const float* __restrict__ dinv,
    const int* __restrict__ rp, const int* __restrict__ srt,
    const float* __restrict__ b1, float* __restrict__ hout, int N)
{
    int wave = threadIdx.x >> 6;
    int lane = threadIdx.x & 63;
    int node = blockIdx.x * 4 + wave;
    if (node >= N) return;
    int s0 = rp[node], s1 = rp[node + 1];
    float2 acc = edge_accum(t, srt, s0, s1, node, lane);
    float di = dinv[node];
    float2 bb = *(const float2*)(b1 + lane * 2);
    float2 o;
    o.x = fmaxf(fmaf(acc.x, di, bb.x), 0.0f);
    o.y = fmaxf(fmaf(acc.y, di, bb.y), 0.0f);
    *(float2*)(hout + (size_t)node * 128 + lane * 2) = o;
}

// Layer-2 aggregation fused with the linear head: per-node scalar h2·Wl,
// shuffle-reduced across the wave, one atomicAdd per node into graph sums.
__global__ __launch_bounds__(256) void k_agg2(
    const unsigned* __restrict__ t, const float* __restrict__ dinv,
    const int* __restrict__ rp, const int* __restrict__ srt,
    const float* __restrict__ b2, const float* __restrict__ Wl,
    const int* __restrict__ batch, float* __restrict__ gsum,
    int* __restrict__ gcnt, int N)
{
    int wave = threadIdx.x >> 6;
    int lane = threadIdx.x & 63;
    int node = blockIdx.x * 4 + wave;
    if (node >= N) return;
    int s0 = rp[node], s1 = rp[node + 1];
    float2 acc = edge_accum(t, srt, s0, s1, node, lane);
    float di = dinv[node];
    float2 bb = *(const float2*)(b2 + lane * 2);
    float2 wl = *(const float2*)(Wl + lane * 2);
    float hx = fmaf(acc.x, di, bb.x);
    float hy = fmaf(acc.y, di, bb.y);
    float p = hx * wl.x + hy * wl.y;
#pragma unroll
    for (int off = 32; off > 0; off >>= 1) p += __shfl_down(p, off);
    if (lane == 0) {
        int g = batch[node];
        atomicAdd(&gsum[g], p);
        atomicAdd(&gcnt[g], 1);
    }
}

__global__ void k_final(const float* __restrict__ gsum, const int* __restrict__ gcnt,
                        const float* __restrict__ bl, float* __restrict__ out, int G) {
    int g = blockIdx.x * blockDim.x + threadIdx.x;
    if (g < G) out[g] = gsum[g] / fmaxf((float)gcnt[g], 1.0f) + bl[0];
}

extern "C" void kernel_launch(void* const* d_in, const int* in_sizes, int n_in,
                              void* d_out, int out_size, void* d_ws, size_t ws_size,
                              hipStream_t stream)
{
    const float* x  = (const float*)d_in[0];
    const int*   ei = (const int*)d_in[1];
    // d_in[2] = edge_attr: unused by the reference
    const int*   batch = (const int*)d_in[3];
    const float* W1 = (const float*)d_in[4];
    const float* b1 = (const float*)d_in[5];
    const float* W2 = (const float*)d_in[6];
    const float* b2 = (const float*)d_in[7];
    const float* Wl = (const float*)d_in[8];
    const float* bl = (const float*)d_in[9];

    int N = in_sizes[0] / 128;
    int E = in_sizes[1] / 2;
    const int* src = ei;
    const int* dst = ei + E;

    char* ws = (char*)d_ws;
    size_t off = 0;
    auto alloc = [&](size_t bytes) -> void* {
        void* p = ws + off;
        off = (off + bytes + 255) & ~(size_t)255;
        return p;
    };
    unsigned* t  = (unsigned*)alloc((size_t)N * 64 * 4);   // bf16 rows (256 B)
    float* h1    = (float*)alloc((size_t)N * 128 * 4);
    int*   srt   = (int*)alloc((size_t)E * 4);
    int*   cnt   = (int*)alloc((size_t)N * 4);
    float* dinv  = (float*)alloc((size_t)N * 4);
    int*   rp    = (int*)alloc((size_t)(N + 1) * 4);
    int*   cur   = (int*)alloc((size_t)N * 4);
    int*   bsum  = (int*)alloc(1024 * 4);
    float* gsum  = (float*)alloc(512 * 4);
    int*   gcnt  = (int*)alloc(512 * 4);
    (void)ws_size;

    hipMemsetAsync(cnt, 0, (size_t)N * 4, stream);
    hipMemsetAsync(gsum, 0, 512 * 4, stream);
    hipMemsetAsync(gcnt, 0, 512 * 4, stream);

    int eb = (E + 255) / 256;
    int nb = (N + 255) / 256;
    k_count<<<eb, 256, 0, stream>>>(dst, cnt, E);
    k_dinv<<<nb, 256, 0, stream>>>(cnt, dinv, N);
    int nchunk = (N + 1023) / 1024;   // 98 <= 128 (k_scan_b capacity)
    k_scan_a<<<nchunk, 1024, 0, stream>>>(cnt, rp, bsum, N);
    k_scan_b<<<1, 128, 0, stream>>>(bsum, nchunk);
    k_scan_c<<<(N + 256) / 256, 256, 0, stream>>>(rp, bsum, cur, N, E);
    k_scatter<<<eb, 256, 0, stream>>>(src, dst, cur, srt, E);

    int mmb = (N + 127) / 128;
    k_mm_scale<<<mmb, 256, 0, stream>>>(x, W1, dinv, t, N);
    k_agg1<<<(N + 3) / 4, 256, 0, stream>>>(t, dinv, rp, srt, b1, h1, N);
    k_mm_scale<<<mmb, 256, 0, stream>>>(h1, W2, dinv, t, N);
    k_agg2<<<(N + 3) / 4, 256, 0, stream>>>(t, dinv, rp, srt, b2, Wl, batch, gsum, gcnt, N);
    k_final<<<2, 256, 0, stream>>>(gsum, gcnt, bl, (float*)d_out, 512);
}